// Round 1
// baseline (604.699 us; speedup 1.0000x reference)
//
#include <hip/hip_runtime.h>
#include <hip/hip_bf16.h>
#include <cstddef>

typedef __attribute__((ext_vector_type(4))) __bf16 bf16x4;
typedef __attribute__((ext_vector_type(8))) __bf16 bf16x8;
typedef __attribute__((ext_vector_type(4))) float f32x4;

#define L_SEQ 2048
#define K_DIM 768
#define M_DIM 768
#define N_BATCH 4
#define N_HEAD 12

// Generic projection GEMM:
//   Out[m, (b,a,l)] = sum_d W[m,d] * X[d, (b,a,l)] + bias[m]
// X logical layout (B, K, A, L)  -> addr = ((b*K + d)*A + a)*L + l
// Out logical layout (B, M, A, L)
// Tile: BM=BN=128, BK=64. 4 waves, each computes a 64x64 quadrant as 4x4
// mfma_f32_16x16x32_bf16 fragments. fp32->bf16 conversion happens during
// LDS staging. LDS rows padded 64->72 bf16 (row stride 144 B = 16B-aligned,
// reduces the stride-128B 16-way bank conflict to 2-way, which is free).
template <typename XT, typename OT>
__global__ __launch_bounds__(256, 2)
void gemm_kernel(const float* __restrict__ W, const float* __restrict__ bias,
                 const XT* __restrict__ X, OT* __restrict__ Out, int A)
{
    __shared__ __bf16 As[128][72];
    __shared__ __bf16 Bs[128][72];

    const int tid = threadIdx.x;
    const int n0 = blockIdx.x * 128;
    const int m0 = blockIdx.y * 128;
    // 128-wide n-tiles never cross a (b,a) chunk boundary (L=2048 % 128 == 0)
    const int chunk = n0 >> 11;
    const int l0 = n0 & (L_SEQ - 1);
    const int b_ = chunk / A;
    const int a_ = chunk % A;
    const size_t dstr = (size_t)A * L_SEQ;                       // stride between d (or m) rows
    const size_t base_x = ((size_t)b_ * K_DIM * A + a_) * L_SEQ;
    const size_t base_o = ((size_t)b_ * M_DIM * A + a_) * L_SEQ;

    const int lane = tid & 63;
    const int wave = tid >> 6;
    const int wr = (wave >> 1) * 64;   // wave row offset in tile
    const int wc = (wave & 1) * 64;    // wave col offset in tile
    const int lr = lane & 15;          // fragment row/col lane index
    const int lk = (lane >> 4) * 8;    // fragment k offset

    f32x4 acc[4][4];
    #pragma unroll
    for (int i = 0; i < 4; ++i)
        #pragma unroll
        for (int j = 0; j < 4; ++j)
            acc[i][j] = (f32x4){0.f, 0.f, 0.f, 0.f};

    const int ar = tid >> 4;          // 0..15 (A-stage row group)
    const int ac4 = (tid & 15) * 4;   // 0..60 (A-stage k quad)
    const int bn = tid & 127;         // B-stage n index
    const int bkg = (tid >> 7) * 4;   // B-stage k group (0 or 4)

    for (int kt = 0; kt < K_DIM; kt += 64) {
        __syncthreads();
        // ---- stage A: W rows m0..m0+127, cols kt..kt+63 (row-major, k-contig)
        #pragma unroll
        for (int p = 0; p < 8; ++p) {
            const int row = p * 16 + ar;
            const float4 w4 = *(const float4*)(W + (size_t)(m0 + row) * K_DIM + kt + ac4);
            bf16x4 t;
            t[0] = (__bf16)w4.x; t[1] = (__bf16)w4.y; t[2] = (__bf16)w4.z; t[3] = (__bf16)w4.w;
            *(bf16x4*)&As[row][ac4] = t;
        }
        // ---- stage B: X k-rows kt..kt+63 x n-cols n0..n0+127, transposed into Bs[n][k]
        // each thread loads 4 k's at one n (4 coalesced-dword loads), packs, 8B ds_write
        #pragma unroll
        for (int p = 0; p < 8; ++p) {
            const int kk = p * 8 + bkg;
            const size_t g = base_x + (size_t)(kt + kk) * dstr + l0 + bn;
            bf16x4 t;
            #pragma unroll
            for (int i = 0; i < 4; ++i)
                t[i] = (__bf16)(X[g + (size_t)i * dstr]);
            *(bf16x4*)&Bs[bn][kk] = t;
        }
        __syncthreads();
        // ---- compute: 2 x K32 sub-steps, 16 mfma each
        #pragma unroll
        for (int ks = 0; ks < 2; ++ks) {
            const int ko = ks * 32 + lk;
            bf16x8 a[4], b[4];
            #pragma unroll
            for (int f = 0; f < 4; ++f)
                a[f] = *(const bf16x8*)&As[wr + f * 16 + lr][ko];
            #pragma unroll
            for (int f = 0; f < 4; ++f)
                b[f] = *(const bf16x8*)&Bs[wc + f * 16 + lr][ko];
            #pragma unroll
            for (int i = 0; i < 4; ++i)
                #pragma unroll
                for (int j = 0; j < 4; ++j)
                    acc[i][j] = __builtin_amdgcn_mfma_f32_16x16x32_bf16(a[i], b[j], acc[i][j], 0, 0, 0);
        }
    }

    // ---- epilogue: C/D mapping (verified m89): col = lane&15, row = (lane>>4)*4 + reg
    const int row0 = (lane >> 4) * 4;
    #pragma unroll
    for (int i = 0; i < 4; ++i) {
        #pragma unroll
        for (int r = 0; r < 4; ++r) {
            const int mg = m0 + wr + i * 16 + row0 + r;
            const float bi = bias[mg];
            #pragma unroll
            for (int j = 0; j < 4; ++j) {
                const int nl = wc + j * 16 + lr;
                Out[base_o + (size_t)mg * dstr + l0 + nl] = (OT)(acc[i][j][r] + bi);
            }
        }
    }
}

// Attention: one thread per (b, h, l). 10 softmax entries:
//   w = 0..4  : local window l-2..l+2 (zero-padded => score 0, value 0, but
//               STILL participates in the softmax, matching the reference)
//   w = 5..9  : cross entries ak/av[al, l]
// q/k/v layout (B, 768, L) bf16; ak/av layout (B, 768, 5, L) bf16.
__global__ __launch_bounds__(256)
void attn_kernel(const __bf16* __restrict__ q, const __bf16* __restrict__ kx,
                 const __bf16* __restrict__ vx, const __bf16* __restrict__ ak,
                 const __bf16* __restrict__ av, __bf16* __restrict__ att)
{
    const int bid = blockIdx.x;
    const int lt = bid & 7;          // L/256 = 8 tiles
    const int bh = bid >> 3;
    const int b = bh / N_HEAD;
    const int h = bh % N_HEAD;
    const int l = lt * 256 + threadIdx.x;

    const size_t cbase = ((size_t)b * 768 + h * 64) * L_SEQ;       // + c*L + l
    const size_t abase = ((size_t)b * 768 + h * 64) * 5 * L_SEQ;   // + c*5*L + al*L + l

    float s[10];
    #pragma unroll
    for (int i = 0; i < 10; ++i) s[i] = 0.f;

    for (int c = 0; c < 64; ++c) {
        const float qc = (float)q[cbase + (size_t)c * L_SEQ + l];
        const __bf16* krow = kx + cbase + (size_t)c * L_SEQ;
        #pragma unroll
        for (int w = 0; w < 5; ++w) {
            const int lw = l + w - 2;
            if (lw >= 0 && lw < L_SEQ) s[w] += qc * (float)krow[lw];
        }
        const __bf16* arow = ak + abase + (size_t)c * 5 * L_SEQ;
        #pragma unroll
        for (int a = 0; a < 5; ++a) s[5 + a] += qc * (float)arow[(size_t)a * L_SEQ + l];
    }

    #pragma unroll
    for (int i = 0; i < 10; ++i) s[i] *= 0.125f;   // 1/sqrt(64)

    float mx = s[0];
    #pragma unroll
    for (int i = 1; i < 10; ++i) mx = fmaxf(mx, s[i]);
    float e[10], sum = 0.f;
    #pragma unroll
    for (int i = 0; i < 10; ++i) { e[i] = expf(s[i] - mx); sum += e[i]; }
    const float inv = 1.f / sum;

    for (int c = 0; c < 64; ++c) {
        float o = 0.f;
        const __bf16* vrow = vx + cbase + (size_t)c * L_SEQ;
        #pragma unroll
        for (int w = 0; w < 5; ++w) {
            const int lw = l + w - 2;
            if (lw >= 0 && lw < L_SEQ) o += e[w] * (float)vrow[lw];
        }
        const __bf16* avrow = av + abase + (size_t)c * 5 * L_SEQ;
        #pragma unroll
        for (int a = 0; a < 5; ++a) o += e[5 + a] * (float)avrow[(size_t)a * L_SEQ + l];
        att[cbase + (size_t)c * L_SEQ + l] = (__bf16)(o * inv);
    }
}

extern "C" void kernel_launch(void* const* d_in, const int* in_sizes, int n_in,
                              void* d_out, int out_size, void* d_ws, size_t ws_size,
                              hipStream_t stream)
{
    const float* x  = (const float*)d_in[0];
    const float* ax = (const float*)d_in[1];
    const float* Wq = (const float*)d_in[2];
    const float* bq = (const float*)d_in[3];
    const float* Wk = (const float*)d_in[4];
    const float* bk = (const float*)d_in[5];
    const float* Wv = (const float*)d_in[6];
    const float* bv = (const float*)d_in[7];
    const float* Wo = (const float*)d_in[8];
    const float* bo = (const float*)d_in[9];
    float* out = (float*)d_out;

    const size_t tokx = (size_t)N_BATCH * 768 * L_SEQ;      // 6.29M elems
    __bf16* q   = (__bf16*)d_ws;
    __bf16* kx  = q   + tokx;
    __bf16* vx  = kx  + tokx;
    __bf16* att = vx  + tokx;
    __bf16* ak  = att + tokx;
    __bf16* av  = ak  + tokx * 5;
    // total ws use: 14 * tokx * 2 B = 176 MB

    const dim3 blk(256);
    const dim3 grid_x(64, 6);    // N = 4*2048 = 8192 -> 64 n-tiles; M=768 -> 6
    const dim3 grid_ax(320, 6);  // N = 4*5*2048 = 40960 -> 320 n-tiles

    gemm_kernel<float, __bf16><<<grid_x,  blk, 0, stream>>>(Wq, bq, x,  q,  1);
    gemm_kernel<float, __bf16><<<grid_x,  blk, 0, stream>>>(Wk, bk, x,  kx, 1);
    gemm_kernel<float, __bf16><<<grid_x,  blk, 0, stream>>>(Wv, bv, x,  vx, 1);
    gemm_kernel<float, __bf16><<<grid_ax, blk, 0, stream>>>(Wk, bk, ax, ak, 5);
    gemm_kernel<float, __bf16><<<grid_ax, blk, 0, stream>>>(Wv, bv, ax, av, 5);

    attn_kernel<<<dim3(N_BATCH * N_HEAD * (L_SEQ / 256)), blk, 0, stream>>>(q, kx, vx, ak, av, att);

    gemm_kernel<__bf16, float><<<grid_x, blk, 0, stream>>>(Wo, bo, att, out, 1);
}

// Round 2
// 388.885 us; speedup vs baseline: 1.5550x; 1.5550x over previous
//
#include <hip/hip_runtime.h>
#include <hip/hip_bf16.h>
#include <cstddef>
#include <cstdint>

typedef __attribute__((ext_vector_type(4))) __bf16 bf16x4;
typedef __attribute__((ext_vector_type(8))) __bf16 bf16x8;
typedef __attribute__((ext_vector_type(4))) float f32x4;

#define L_SEQ 2048
#define KD 768           // inner dim (nhid)
#define N_HEAD 12
#define NB 4
#define NX 8192          // B*L
#define NALL 49152       // B*L*(1+5)

// 16B async global->LDS. LDS dest is wave-uniform base + lane*16.
__device__ __forceinline__ void gload16(const __bf16* g, __bf16* l) {
    __builtin_amdgcn_global_load_lds(
        (const __attribute__((address_space(1))) void*)g,
        (__attribute__((address_space(3))) void*)l, 16, 0, 0);
}

// ---------------- weight fp32 -> bf16 (4 matrices of 768x768) ----------------
__global__ __launch_bounds__(256) void wconv_kernel(
    const float* __restrict__ W0, const float* __restrict__ W1,
    const float* __restrict__ W2, const float* __restrict__ W3,
    __bf16* __restrict__ O0, __bf16* __restrict__ O1,
    __bf16* __restrict__ O2, __bf16* __restrict__ O3)
{
    const float* src; __bf16* dst;
    switch (blockIdx.y) {
        case 0: src = W0; dst = O0; break;
        case 1: src = W1; dst = O1; break;
        case 2: src = W2; dst = O2; break;
        default: src = W3; dst = O3; break;
    }
    const int i = (blockIdx.x * 256 + threadIdx.x) * 4;   // 576 blocks * 1024 = 589824
    const float4 v = *(const float4*)(src + i);
    bf16x4 t;
    t[0] = (__bf16)v.x; t[1] = (__bf16)v.y; t[2] = (__bf16)v.z; t[3] = (__bf16)v.w;
    *(bf16x4*)(dst + i) = t;
}

// ------------- convert+transpose one a'-chunk into chunkT[n(8192)][768] -------------
// a'=0 -> x (b,768,L); a'>=1 -> ax (b,768,5,L) slice a'-1. Output row n=b*2048+l, k-major.
__global__ __launch_bounds__(256) void xconv_kernel(
    const float* __restrict__ x, const float* __restrict__ ax,
    __bf16* __restrict__ chunkT, int aprime)
{
    __shared__ __bf16 S[64][72];      // [l][d], padded
    const int t = threadIdx.x;
    const int bb = blockIdx.x >> 5;
    const int l0 = (blockIdx.x & 31) * 64;
    const int d0 = blockIdx.y * 64;
    const int r = t >> 4;             // 0..15
    const int c4 = (t & 15) * 4;      // 0..60
    #pragma unroll
    for (int p = 0; p < 4; ++p) {
        const int d = d0 + r + p * 16;
        const float* src = (aprime == 0)
            ? x + ((size_t)(bb * KD + d)) * L_SEQ
            : ax + (((size_t)(bb * KD + d)) * 5 + (aprime - 1)) * L_SEQ;
        const float4 v = *(const float4*)(src + l0 + c4);
        S[c4 + 0][r + p * 16] = (__bf16)v.x;
        S[c4 + 1][r + p * 16] = (__bf16)v.y;
        S[c4 + 2][r + p * 16] = (__bf16)v.z;
        S[c4 + 3][r + p * 16] = (__bf16)v.w;
    }
    __syncthreads();
    #pragma unroll
    for (int p = 0; p < 4; ++p) {
        const int lr = r + p * 16;
        const bf16x4 v = *(const bf16x4*)&S[lr][c4];
        *(bf16x4*)(chunkT + ((size_t)bb * L_SEQ + l0 + lr) * KD + d0 + c4) = v;
    }
}

// ---------------- m97-style GEMM body: Out[m,n] = sum_d A[m,d]*Bt[n,d] + bias[m] ----------------
// 128x128 tile, BK=64, 4 waves, global_load_lds(16B) staging, linear LDS.
template <int MODE>   // 0: bf16 Out[m*ldn + n]; 1: fp32 final out[(b*768+m)*2048 + l], n=b*2048+l
__device__ __forceinline__ void gemm_body(
    const __bf16* __restrict__ A, const __bf16* __restrict__ Bt,
    const float* __restrict__ bias, void* __restrict__ Out,
    size_t ldn, int m0, int n0, __bf16* As, __bf16* Bs)
{
    const int tid = threadIdx.x;
    const int lane = tid & 63, wave = tid >> 6;
    const int wr = (wave >> 1) * 64, wc = (wave & 1) * 64;
    const int lr = lane & 15, lk = (lane >> 4) * 8;
    const int srow = lane >> 3;          // 0..7
    const int skq = (lane & 7) * 8;      // 0..56

    f32x4 acc[4][4];
    #pragma unroll
    for (int i = 0; i < 4; ++i)
        #pragma unroll
        for (int j = 0; j < 4; ++j)
            acc[i][j] = (f32x4){0.f, 0.f, 0.f, 0.f};

    for (int kt = 0; kt < KD; kt += 64) {
        __syncthreads();
        #pragma unroll
        for (int p = 0; p < 4; ++p) {
            const int rb = wave * 32 + p * 8;                       // wave-uniform
            gload16(A  + (size_t)(m0 + rb + srow) * KD + kt + skq, As + rb * 64);
            gload16(Bt + (size_t)(n0 + rb + srow) * KD + kt + skq, Bs + rb * 64);
        }
        __syncthreads();
        #pragma unroll
        for (int ks = 0; ks < 2; ++ks) {
            const int ko = ks * 32 + lk;
            bf16x8 a[4], b[4];
            #pragma unroll
            for (int f = 0; f < 4; ++f) a[f] = *(const bf16x8*)(As + (wr + f * 16 + lr) * 64 + ko);
            #pragma unroll
            for (int f = 0; f < 4; ++f) b[f] = *(const bf16x8*)(Bs + (wc + f * 16 + lr) * 64 + ko);
            #pragma unroll
            for (int i = 0; i < 4; ++i)
                #pragma unroll
                for (int j = 0; j < 4; ++j)
                    acc[i][j] = __builtin_amdgcn_mfma_f32_16x16x32_bf16(a[i], b[j], acc[i][j], 0, 0, 0);
        }
    }

    const int row0 = (lane >> 4) * 4;   // C/D: col=lane&15, row=(lane>>4)*4+reg
    #pragma unroll
    for (int i = 0; i < 4; ++i) {
        #pragma unroll
        for (int r = 0; r < 4; ++r) {
            const int mg = m0 + wr + i * 16 + row0 + r;
            const float bi = bias[mg];
            #pragma unroll
            for (int j = 0; j < 4; ++j) {
                const int nl = wc + j * 16 + lr;
                if (MODE == 0) {
                    ((__bf16*)Out)[(size_t)mg * ldn + n0 + nl] = (__bf16)(acc[i][j][r] + bi);
                } else {
                    const int b_ = n0 >> 11, lo = (n0 & 2047) + nl;
                    ((float*)Out)[((size_t)(b_ * KD + mg)) * L_SEQ + lo] = acc[i][j][r] + bi;
                }
            }
        }
    }
}

// fused K+V projection for one a'-chunk (grid y: 0..5 -> K, 6..11 -> V)
__global__ __launch_bounds__(256, 2) void gemm_kv(
    const __bf16* __restrict__ Wk, const __bf16* __restrict__ Wv,
    const float* __restrict__ bk, const float* __restrict__ bv,
    const __bf16* __restrict__ chunkT, __bf16* __restrict__ OutK, __bf16* __restrict__ OutV)
{
    __shared__ __bf16 As[8192], Bs[8192];
    const int n0 = blockIdx.x * 128;
    if (blockIdx.y < 6)
        gemm_body<0>(Wk, chunkT, bk, OutK, NALL, blockIdx.y * 128, n0, As, Bs);
    else
        gemm_body<0>(Wv, chunkT, bv, OutV, NALL, (blockIdx.y - 6) * 128, n0, As, Bs);
}

__global__ __launch_bounds__(256, 2) void gemm_q(
    const __bf16* __restrict__ Wq, const float* __restrict__ bq,
    const __bf16* __restrict__ chunkT, __bf16* __restrict__ OutQ)
{
    __shared__ __bf16 As[8192], Bs[8192];
    gemm_body<0>(Wq, chunkT, bq, OutQ, NX, blockIdx.y * 128, blockIdx.x * 128, As, Bs);
}

__global__ __launch_bounds__(256, 2) void gemm_o(
    const __bf16* __restrict__ Wo, const float* __restrict__ bo,
    const __bf16* __restrict__ attT, float* __restrict__ out)
{
    __shared__ __bf16 As[8192], Bs[8192];
    gemm_body<1>(Wo, attT, bo, out, 0, blockIdx.y * 128, blockIdx.x * 128, As, Bs);
}

// ---------------- attention ----------------
// Q: [m][8192]  (m=h*64+c, n=b*2048+l)
// K,V: [m][49152] (n = a'*8192 + b*2048 + l; a'=0 local, a'=1..5 cross)
// attT out: [n(8192)][768]
// Block: 256 thr = 4 waves; wave handles 16 l, lane = cg*16 + loff; cg owns 16 channels.
__global__ __launch_bounds__(256) void attn_kernel(
    const __bf16* __restrict__ Q, const __bf16* __restrict__ K,
    const __bf16* __restrict__ V, __bf16* __restrict__ attT)
{
    const int bid = blockIdx.x;
    const int lt = bid & 31;
    const int h = (bid >> 5) % N_HEAD;
    const int b = bid / (N_HEAD * 32);
    const int tid = threadIdx.x;
    const int wave = tid >> 6, lane = tid & 63;
    const int loff = lane & 15, cg = lane >> 4;
    const int l = lt * 64 + wave * 16 + loff;

    const size_t qb = ((size_t)h * 64 + cg * 16) * NX + b * L_SEQ;
    const size_t kb = ((size_t)h * 64 + cg * 16) * NALL + b * L_SEQ;

    float s[10];
    #pragma unroll
    for (int i = 0; i < 10; ++i) s[i] = 0.f;

    #pragma unroll
    for (int cc = 0; cc < 16; ++cc) {
        const float qc = (float)Q[qb + (size_t)cc * NX + l];
        const __bf16* kr = K + kb + (size_t)cc * NALL;
        #pragma unroll
        for (int w = 0; w < 5; ++w) {
            const int lw = l + w - 2;
            if (lw >= 0 && lw < L_SEQ) s[w] += qc * (float)kr[lw];
        }
        #pragma unroll
        for (int a = 0; a < 5; ++a)
            s[5 + a] += qc * (float)kr[(size_t)(a + 1) * NX + l];
    }

    #pragma unroll
    for (int i = 0; i < 10; ++i) {
        s[i] += __shfl_xor(s[i], 16);
        s[i] += __shfl_xor(s[i], 32);
        s[i] *= 0.125f;                   // 1/sqrt(64)
    }

    float mx = s[0];
    #pragma unroll
    for (int i = 1; i < 10; ++i) mx = fmaxf(mx, s[i]);
    float e[10], sum = 0.f;
    #pragma unroll
    for (int i = 0; i < 10; ++i) { e[i] = __expf(s[i] - mx); sum += e[i]; }
    const float inv = 1.f / sum;

    float o[16];
    #pragma unroll
    for (int i = 0; i < 16; ++i) o[i] = 0.f;
    #pragma unroll
    for (int cc = 0; cc < 16; ++cc) {
        const __bf16* vr = V + kb + (size_t)cc * NALL;
        float acc = 0.f;
        #pragma unroll
        for (int w = 0; w < 5; ++w) {
            const int lw = l + w - 2;
            if (lw >= 0 && lw < L_SEQ) acc += e[w] * (float)vr[lw];
        }
        #pragma unroll
        for (int a = 0; a < 5; ++a)
            acc += e[5 + a] * (float)vr[(size_t)(a + 1) * NX + l];
        o[cc] = acc;
    }

    __bf16* dst = attT + ((size_t)b * L_SEQ + l) * KD + h * 64 + cg * 16;
    bf16x8 t0, t1;
    #pragma unroll
    for (int i = 0; i < 8; ++i) {
        t0[i] = (__bf16)(o[i] * inv);
        t1[i] = (__bf16)(o[8 + i] * inv);
    }
    *(bf16x8*)dst = t0;
    *(bf16x8*)(dst + 8) = t1;
}

extern "C" void kernel_launch(void* const* d_in, const int* in_sizes, int n_in,
                              void* d_out, int out_size, void* d_ws, size_t ws_size,
                              hipStream_t stream)
{
    const float* x  = (const float*)d_in[0];
    const float* ax = (const float*)d_in[1];
    const float* Wq = (const float*)d_in[2];
    const float* bq = (const float*)d_in[3];
    const float* Wk = (const float*)d_in[4];
    const float* bk = (const float*)d_in[5];
    const float* Wv = (const float*)d_in[6];
    const float* bv = (const float*)d_in[7];
    const float* Wo = (const float*)d_in[8];
    const float* bo = (const float*)d_in[9];
    float* out = (float*)d_out;

    // ws layout (bf16 elems): 4 weights + Q + K + V + chunkT(/attT alias)
    __bf16* p = (__bf16*)d_ws;
    __bf16* Wq_bf = p; p += 589824;
    __bf16* Wk_bf = p; p += 589824;
    __bf16* Wv_bf = p; p += 589824;
    __bf16* Wo_bf = p; p += 589824;
    __bf16* Qb    = p; p += (size_t)KD * NX;      // 6.29M
    __bf16* Kall  = p; p += (size_t)KD * NALL;    // 37.7M
    __bf16* Vall  = p; p += (size_t)KD * NALL;    // 37.7M
    __bf16* chunkT = p;                            // 6.29M (reused as attT)
    __bf16* attT = chunkT;

    const dim3 blk(256);

    wconv_kernel<<<dim3(576, 4), blk, 0, stream>>>(Wq, Wk, Wv, Wo, Wq_bf, Wk_bf, Wv_bf, Wo_bf);

    for (int ap = 0; ap < 6; ++ap) {
        xconv_kernel<<<dim3(128, 12), blk, 0, stream>>>(x, ax, chunkT, ap);
        gemm_kv<<<dim3(64, 12), blk, 0, stream>>>(Wk_bf, Wv_bf, bk, bv, chunkT,
                                                  Kall + (size_t)ap * NX, Vall + (size_t)ap * NX);
        if (ap == 0)
            gemm_q<<<dim3(64, 6), blk, 0, stream>>>(Wq_bf, bq, chunkT, Qb);
    }

    attn_kernel<<<dim3(NB * N_HEAD * (L_SEQ / 64)), blk, 0, stream>>>(Qb, Kall, Vall, attT);

    gemm_o<<<dim3(64, 6), blk, 0, stream>>>(Wo_bf, bo, attT, out);
}

// Round 3
// 356.666 us; speedup vs baseline: 1.6954x; 1.0903x over previous
//
#include <hip/hip_runtime.h>
#include <hip/hip_bf16.h>
#include <cstddef>
#include <cstdint>

typedef __attribute__((ext_vector_type(4))) __bf16 bf16x4;
typedef __attribute__((ext_vector_type(8))) __bf16 bf16x8;
typedef __attribute__((ext_vector_type(4))) float f32x4;

#define L_SEQ 2048
#define KD 768           // inner dim (nhid)
#define N_HEAD 12
#define NB 4
#define NX 8192          // B*L
#define NALL 49152       // B*L*(1+5)

// 16B async global->LDS. LDS dest is wave-uniform base + lane*16.
__device__ __forceinline__ void gload16(const __bf16* g, __bf16* l) {
    __builtin_amdgcn_global_load_lds(
        (const __attribute__((address_space(1))) void*)g,
        (__attribute__((address_space(3))) void*)l, 16, 0, 0);
}

// ---------------- weight fp32 -> bf16 (4 matrices of 768x768) ----------------
__global__ __launch_bounds__(256) void wconv_kernel(
    const float* __restrict__ W0, const float* __restrict__ W1,
    const float* __restrict__ W2, const float* __restrict__ W3,
    __bf16* __restrict__ O0, __bf16* __restrict__ O1,
    __bf16* __restrict__ O2, __bf16* __restrict__ O3)
{
    const float* src; __bf16* dst;
    switch (blockIdx.y) {
        case 0: src = W0; dst = O0; break;
        case 1: src = W1; dst = O1; break;
        case 2: src = W2; dst = O2; break;
        default: src = W3; dst = O3; break;
    }
    const int i = (blockIdx.x * 256 + threadIdx.x) * 4;
    const float4 v = *(const float4*)(src + i);
    bf16x4 t;
    t[0] = (__bf16)v.x; t[1] = (__bf16)v.y; t[2] = (__bf16)v.z; t[3] = (__bf16)v.w;
    *(bf16x4*)(dst + i) = t;
}

// ------------- convert+transpose one a'-chunk into chunkT[n(8192)][768] -------------
__global__ __launch_bounds__(256) void xconv_kernel(
    const float* __restrict__ x, const float* __restrict__ ax,
    __bf16* __restrict__ chunkT, int aprime)
{
    __shared__ __bf16 S[64][72];
    const int t = threadIdx.x;
    const int bb = blockIdx.x >> 5;
    const int l0 = (blockIdx.x & 31) * 64;
    const int d0 = blockIdx.y * 64;
    const int r = t >> 4;
    const int c4 = (t & 15) * 4;
    #pragma unroll
    for (int p = 0; p < 4; ++p) {
        const int d = d0 + r + p * 16;
        const float* src = (aprime == 0)
            ? x + ((size_t)(bb * KD + d)) * L_SEQ
            : ax + (((size_t)(bb * KD + d)) * 5 + (aprime - 1)) * L_SEQ;
        const float4 v = *(const float4*)(src + l0 + c4);
        S[c4 + 0][r + p * 16] = (__bf16)v.x;
        S[c4 + 1][r + p * 16] = (__bf16)v.y;
        S[c4 + 2][r + p * 16] = (__bf16)v.z;
        S[c4 + 3][r + p * 16] = (__bf16)v.w;
    }
    __syncthreads();
    #pragma unroll
    for (int p = 0; p < 4; ++p) {
        const int lr = r + p * 16;
        const bf16x4 v = *(const bf16x4*)&S[lr][c4];
        *(bf16x4*)(chunkT + ((size_t)bb * L_SEQ + l0 + lr) * KD + d0 + c4) = v;
    }
}

// ---------------- m97-style GEMM: Out = A * Bt^T + bias ----------------
// MODE 0: bf16 transposed out OutT[(n0+nl)*768 + m]  (LDS-transposed epilogue)
// MODE 1: fp32 final out[(b*768+m)*2048 + l], n = b*2048+l
template <int MODE>
__device__ __forceinline__ void gemm_body(
    const __bf16* __restrict__ A, const __bf16* __restrict__ Bt,
    const float* __restrict__ bias, void* __restrict__ Out,
    int m0, int n0, __bf16* LDS)
{
    __bf16* As = LDS;
    __bf16* Bs = LDS + 8192;
    const int tid = threadIdx.x;
    const int lane = tid & 63, wave = tid >> 6;
    const int wr = (wave >> 1) * 64, wc = (wave & 1) * 64;
    const int lr = lane & 15, lk = (lane >> 4) * 8;
    const int srow = lane >> 3;
    const int skq = (lane & 7) * 8;

    f32x4 acc[4][4];
    #pragma unroll
    for (int i = 0; i < 4; ++i)
        #pragma unroll
        for (int j = 0; j < 4; ++j)
            acc[i][j] = (f32x4){0.f, 0.f, 0.f, 0.f};

    for (int kt = 0; kt < KD; kt += 64) {
        __syncthreads();
        #pragma unroll
        for (int p = 0; p < 4; ++p) {
            const int rb = wave * 32 + p * 8;
            gload16(A  + (size_t)(m0 + rb + srow) * KD + kt + skq, As + rb * 64);
            gload16(Bt + (size_t)(n0 + rb + srow) * KD + kt + skq, Bs + rb * 64);
        }
        __syncthreads();
        #pragma unroll
        for (int ks = 0; ks < 2; ++ks) {
            const int ko = ks * 32 + lk;
            bf16x8 a[4], b[4];
            #pragma unroll
            for (int f = 0; f < 4; ++f) a[f] = *(const bf16x8*)(As + (wr + f * 16 + lr) * 64 + ko);
            #pragma unroll
            for (int f = 0; f < 4; ++f) b[f] = *(const bf16x8*)(Bs + (wc + f * 16 + lr) * 64 + ko);
            #pragma unroll
            for (int i = 0; i < 4; ++i)
                #pragma unroll
                for (int j = 0; j < 4; ++j)
                    acc[i][j] = __builtin_amdgcn_mfma_f32_16x16x32_bf16(a[i], b[j], acc[i][j], 0, 0, 0);
        }
    }

    const int row0 = (lane >> 4) * 4;   // C/D: col=lane&15, row=(lane>>4)*4+reg

    if (MODE == 0) {
        // transpose via LDS (reuse staging buffer), then coalesced 16B writes
        __syncthreads();
        #pragma unroll
        for (int i = 0; i < 4; ++i) {
            #pragma unroll
            for (int r = 0; r < 4; ++r) {
                const int mm = wr + i * 16 + row0 + r;
                const float bi = bias[m0 + mm];
                #pragma unroll
                for (int j = 0; j < 4; ++j) {
                    const int nl = wc + j * 16 + lr;
                    LDS[nl * 136 + mm] = (__bf16)(acc[i][j][r] + bi);
                }
            }
        }
        __syncthreads();
        __bf16* OutT = (__bf16*)Out;
        const int rown = tid >> 1;
        const int coff = (tid & 1) * 64;
        #pragma unroll
        for (int s = 0; s < 8; ++s) {
            const bf16x8 v = *(const bf16x8*)(LDS + rown * 136 + coff + s * 8);
            *(bf16x8*)(OutT + (size_t)(n0 + rown) * KD + m0 + coff + s * 8) = v;
        }
    } else {
        #pragma unroll
        for (int i = 0; i < 4; ++i) {
            #pragma unroll
            for (int r = 0; r < 4; ++r) {
                const int mg = m0 + wr + i * 16 + row0 + r;
                const float bi = bias[mg];
                #pragma unroll
                for (int j = 0; j < 4; ++j) {
                    const int nl = wc + j * 16 + lr;
                    const int b_ = n0 >> 11, lo = (n0 & 2047) + nl;
                    ((float*)Out)[((size_t)(b_ * KD + mg)) * L_SEQ + lo] = acc[i][j][r] + bi;
                }
            }
        }
    }
}

// fused K+V projection for one a'-chunk (grid y: 0..5 -> K, 6..11 -> V)
__global__ __launch_bounds__(256, 2) void gemm_kv(
    const __bf16* __restrict__ Wk, const __bf16* __restrict__ Wv,
    const float* __restrict__ bk, const float* __restrict__ bv,
    const __bf16* __restrict__ chunkT, __bf16* __restrict__ OutKt, __bf16* __restrict__ OutVt)
{
    __shared__ __bf16 LDS[17408];
    const int n0 = blockIdx.x * 128;
    if (blockIdx.y < 6)
        gemm_body<0>(Wk, chunkT, bk, OutKt, blockIdx.y * 128, n0, LDS);
    else
        gemm_body<0>(Wv, chunkT, bv, OutVt, (blockIdx.y - 6) * 128, n0, LDS);
}

__global__ __launch_bounds__(256, 2) void gemm_q(
    const __bf16* __restrict__ Wq, const float* __restrict__ bq,
    const __bf16* __restrict__ chunkT, __bf16* __restrict__ OutQt)
{
    __shared__ __bf16 LDS[17408];
    gemm_body<0>(Wq, chunkT, bq, OutQt, blockIdx.y * 128, blockIdx.x * 128, LDS);
}

__global__ __launch_bounds__(256, 2) void gemm_o(
    const __bf16* __restrict__ Wo, const float* __restrict__ bo,
    const __bf16* __restrict__ attT, float* __restrict__ out)
{
    __shared__ __bf16 LDS[17408];
    gemm_body<1>(Wo, attT, bo, out, blockIdx.y * 128, blockIdx.x * 128, LDS);
}

// ---------------- attention (all transposed, 16B loads) ----------------
// Qt: [8192][768], Kt/Vt: [49152][768] (row n' = a'*8192 + b*2048 + l), attT: [8192][768]
// thread: one (n, head, half-of-64ch). lane = half*32 + ln; wave covers 32 n.
__global__ __launch_bounds__(256) void attn_kernel(
    const __bf16* __restrict__ Qt, const __bf16* __restrict__ Kt,
    const __bf16* __restrict__ Vt, __bf16* __restrict__ attT)
{
    const int bid = blockIdx.x;          // 64 n-tiles * 12 heads
    const int lt = bid & 63;
    const int h = bid >> 6;
    const int tid = threadIdx.x;
    const int wave = tid >> 6, lane = tid & 63;
    const int half = lane >> 5, ln = lane & 31;
    const int n = lt * 128 + wave * 32 + ln;
    const int l = n & (L_SEQ - 1);
    const int c0 = h * 64 + half * 32;

    float q[32];
    {
        const __bf16* qp = Qt + (size_t)n * KD + c0;
        #pragma unroll
        for (int s = 0; s < 4; ++s) {
            const bf16x8 v = *(const bf16x8*)(qp + s * 8);
            #pragma unroll
            for (int j = 0; j < 8; ++j) q[s * 8 + j] = (float)v[j];
        }
    }

    float sc[10];
    #pragma unroll
    for (int w = 0; w < 5; ++w) {
        const int lw = l + w - 2;
        float acc = 0.f;
        if ((unsigned)lw < L_SEQ) {
            const __bf16* kp = Kt + (size_t)(n + w - 2) * KD + c0;
            #pragma unroll
            for (int s = 0; s < 4; ++s) {
                const bf16x8 v = *(const bf16x8*)(kp + s * 8);
                #pragma unroll
                for (int j = 0; j < 8; ++j) acc += q[s * 8 + j] * (float)v[j];
            }
        }
        sc[w] = acc;
    }
    #pragma unroll
    for (int a = 0; a < 5; ++a) {
        const __bf16* kp = Kt + ((size_t)(a + 1) * NX + n) * KD + c0;
        float acc = 0.f;
        #pragma unroll
        for (int s = 0; s < 4; ++s) {
            const bf16x8 v = *(const bf16x8*)(kp + s * 8);
            #pragma unroll
            for (int j = 0; j < 8; ++j) acc += q[s * 8 + j] * (float)v[j];
        }
        sc[5 + a] = acc;
    }

    #pragma unroll
    for (int i = 0; i < 10; ++i) {
        sc[i] += __shfl_xor(sc[i], 32);
        sc[i] *= 0.125f;                   // 1/sqrt(64)
    }

    float mx = sc[0];
    #pragma unroll
    for (int i = 1; i < 10; ++i) mx = fmaxf(mx, sc[i]);
    float e[10], sum = 0.f;
    #pragma unroll
    for (int i = 0; i < 10; ++i) { e[i] = __expf(sc[i] - mx); sum += e[i]; }
    const float inv = 1.f / sum;

    float o[32];
    #pragma unroll
    for (int i = 0; i < 32; ++i) o[i] = 0.f;

    #pragma unroll
    for (int w = 0; w < 5; ++w) {
        const int lw = l + w - 2;
        if ((unsigned)lw < L_SEQ) {
            const __bf16* vp = Vt + (size_t)(n + w - 2) * KD + c0;
            #pragma unroll
            for (int s = 0; s < 4; ++s) {
                const bf16x8 v = *(const bf16x8*)(vp + s * 8);
                #pragma unroll
                for (int j = 0; j < 8; ++j) o[s * 8 + j] += e[w] * (float)v[j];
            }
        }
    }
    #pragma unroll
    for (int a = 0; a < 5; ++a) {
        const __bf16* vp = Vt + ((size_t)(a + 1) * NX + n) * KD + c0;
        #pragma unroll
        for (int s = 0; s < 4; ++s) {
            const bf16x8 v = *(const bf16x8*)(vp + s * 8);
            #pragma unroll
            for (int j = 0; j < 8; ++j) o[s * 8 + j] += e[5 + a] * (float)v[j];
        }
    }

    __bf16* dst = attT + (size_t)n * KD + c0;
    #pragma unroll
    for (int s = 0; s < 4; ++s) {
        bf16x8 t;
        #pragma unroll
        for (int j = 0; j < 8; ++j) t[j] = (__bf16)(o[s * 8 + j] * inv);
        *(bf16x8*)(dst + s * 8) = t;
    }
}

extern "C" void kernel_launch(void* const* d_in, const int* in_sizes, int n_in,
                              void* d_out, int out_size, void* d_ws, size_t ws_size,
                              hipStream_t stream)
{
    const float* x  = (const float*)d_in[0];
    const float* ax = (const float*)d_in[1];
    const float* Wq = (const float*)d_in[2];
    const float* bq = (const float*)d_in[3];
    const float* Wk = (const float*)d_in[4];
    const float* bk = (const float*)d_in[5];
    const float* Wv = (const float*)d_in[6];
    const float* bv = (const float*)d_in[7];
    const float* Wo = (const float*)d_in[8];
    const float* bo = (const float*)d_in[9];
    float* out = (float*)d_out;

    __bf16* p = (__bf16*)d_ws;
    __bf16* Wq_bf = p; p += 589824;
    __bf16* Wk_bf = p; p += 589824;
    __bf16* Wv_bf = p; p += 589824;
    __bf16* Wo_bf = p; p += 589824;
    __bf16* Qt    = p; p += (size_t)KD * NX;
    __bf16* Kt    = p; p += (size_t)KD * NALL;
    __bf16* Vt    = p; p += (size_t)KD * NALL;
    __bf16* chunkT = p;
    __bf16* attT = chunkT;

    const dim3 blk(256);

    wconv_kernel<<<dim3(576, 4), blk, 0, stream>>>(Wq, Wk, Wv, Wo, Wq_bf, Wk_bf, Wv_bf, Wo_bf);

    for (int ap = 0; ap < 6; ++ap) {
        xconv_kernel<<<dim3(128, 12), blk, 0, stream>>>(x, ax, chunkT, ap);
        gemm_kv<<<dim3(64, 12), blk, 0, stream>>>(Wk_bf, Wv_bf, bk, bv, chunkT,
                                                  Kt + (size_t)ap * NX * KD,
                                                  Vt + (size_t)ap * NX * KD);
        if (ap == 0)
            gemm_q<<<dim3(64, 6), blk, 0, stream>>>(Wq_bf, bq, chunkT, Qt);
    }

    attn_kernel<<<dim3(64 * N_HEAD), blk, 0, stream>>>(Qt, Kt, Vt, attT);

    gemm_o<<<dim3(64, 6), blk, 0, stream>>>(Wo_bf, bo, attT, out);
}

// Round 4
// 303.247 us; speedup vs baseline: 1.9941x; 1.1762x over previous
//
#include <hip/hip_runtime.h>
#include <hip/hip_bf16.h>
#include <cstddef>
#include <cstdint>

typedef __attribute__((ext_vector_type(4))) __bf16 bf16x4;
typedef __attribute__((ext_vector_type(8))) __bf16 bf16x8;
typedef __attribute__((ext_vector_type(4))) float f32x4;

#define L_SEQ 2048
#define KD 768           // inner dim (nhid)
#define N_HEAD 12
#define NB 4
#define NX 8192          // B*L
#define NALL 49152       // B*L*(1+5)
#define NT_STEPS 24      // KD / 32

// 16B async global->LDS. LDS dest is wave-uniform base + lane*16.
__device__ __forceinline__ void gload16(const __bf16* g, __bf16* l) {
    __builtin_amdgcn_global_load_lds(
        (const __attribute__((address_space(1))) void*)g,
        (__attribute__((address_space(3))) void*)l, 16, 0, 0);
}

// ---------------- weight fp32 -> bf16 (4 matrices of 768x768) ----------------
__global__ __launch_bounds__(256) void wconv_kernel(
    const float* __restrict__ W0, const float* __restrict__ W1,
    const float* __restrict__ W2, const float* __restrict__ W3,
    __bf16* __restrict__ O0, __bf16* __restrict__ O1,
    __bf16* __restrict__ O2, __bf16* __restrict__ O3)
{
    const float* src; __bf16* dst;
    switch (blockIdx.y) {
        case 0: src = W0; dst = O0; break;
        case 1: src = W1; dst = O1; break;
        case 2: src = W2; dst = O2; break;
        default: src = W3; dst = O3; break;
    }
    const int i = (blockIdx.x * 256 + threadIdx.x) * 4;
    const float4 v = *(const float4*)(src + i);
    bf16x4 t;
    t[0] = (__bf16)v.x; t[1] = (__bf16)v.y; t[2] = (__bf16)v.z; t[3] = (__bf16)v.w;
    *(bf16x4*)(dst + i) = t;
}

// ------------- convert+transpose all 6 a'-chunks into XT[n'(49152)][768] -------------
// n' = ap*8192 + b*2048 + l.  ap=0 -> x, ap>=1 -> ax slice ap-1.
__global__ __launch_bounds__(256) void xconv_kernel(
    const float* __restrict__ x, const float* __restrict__ ax,
    __bf16* __restrict__ XT)
{
    __shared__ __bf16 S[64][72];
    const int t = threadIdx.x;
    const int ap = blockIdx.x >> 7;
    const int inner = blockIdx.x & 127;
    const int bb = inner >> 5;
    const int l0 = (inner & 31) * 64;
    const int d0 = blockIdx.y * 64;
    const int r = t >> 4;
    const int c4 = (t & 15) * 4;
    #pragma unroll
    for (int p = 0; p < 4; ++p) {
        const int d = d0 + r + p * 16;
        const float* src = (ap == 0)
            ? x + ((size_t)(bb * KD + d)) * L_SEQ
            : ax + (((size_t)(bb * KD + d)) * 5 + (ap - 1)) * L_SEQ;
        const float4 v = *(const float4*)(src + l0 + c4);
        S[c4 + 0][r + p * 16] = (__bf16)v.x;
        S[c4 + 1][r + p * 16] = (__bf16)v.y;
        S[c4 + 2][r + p * 16] = (__bf16)v.z;
        S[c4 + 3][r + p * 16] = (__bf16)v.w;
    }
    __syncthreads();
    #pragma unroll
    for (int p = 0; p < 4; ++p) {
        const int lr = r + p * 16;
        const bf16x4 v = *(const bf16x4*)&S[lr][c4];
        *(bf16x4*)(XT + ((size_t)ap * NX + bb * L_SEQ + l0 + lr) * KD + d0 + c4) = v;
    }
}

// ---------------- 256x256 BK=32 quad-buffered counted-vmcnt GEMM ----------------
// Out = A(row-major [M][K]) * Bt(row-major [N][K])^T + bias.
// 512 thr = 8 waves (2M x 4N); per-wave 128x64 out = acc[8][4] f32x4.
// LDS: 4 bufs x (A 16KB + B 16KB) = 128 KiB. XOR swizzle: 16B-slot ^= row&3,
// applied on the pre-swizzled global source (linear global_load_lds dest) and
// on the ds_read address (involution both sides).
// Schedule per K-step: vmcnt(8) -> s_barrier -> stage(t+3) -> ds_read(t) -> 32 MFMA.
template <int MODE>   // 0: bf16 OutT[n'][768] (LDS-transposed); 1: fp32 out[(b*768+m)*2048+l]
__device__ __forceinline__ void gemm256_body(
    const __bf16* __restrict__ A, const __bf16* __restrict__ Bt,
    const float* __restrict__ bias, void* __restrict__ Out,
    int m0, int n0, __bf16* SL)
{
    const int tid = threadIdx.x;
    const int lane = tid & 63, wv = tid >> 6;
    const int wm = wv >> 2, wn = wv & 3;
    const int lr = lane & 15;
    const int kslc = lane >> 4;              // 0..3 (k-slot of MFMA frag)
    const int slotp = kslc ^ (lr & 3);       // swizzled slot for ds_read
    const int srow = lane >> 2;              // staging: row within 16-row chunk
    const int skoff = ((lane & 3) ^ ((lane >> 2) & 3)) * 8;  // swizzled src k-el offset

    f32x4 acc[8][4];
    #pragma unroll
    for (int i = 0; i < 8; ++i)
        #pragma unroll
        for (int j = 0; j < 4; ++j)
            acc[i][j] = (f32x4){0.f, 0.f, 0.f, 0.f};

    auto STAGE = [&](int t) {
        const int bufo = (t & 3) * 16384;
        const int k0 = t * 32;
        #pragma unroll
        for (int i = 0; i < 2; ++i) {
            const int c = wv + i * 8;               // wave-uniform chunk id
            const int row = c * 16 + srow;
            gload16(A  + (size_t)(m0 + row) * KD + k0 + skoff, SL + bufo + c * 512);
            gload16(Bt + (size_t)(n0 + row) * KD + k0 + skoff, SL + bufo + 8192 + c * 512);
        }
    };

    STAGE(0); STAGE(1); STAGE(2);

    #pragma unroll
    for (int t = 0; t < NT_STEPS; ++t) {
        if (t < NT_STEPS - 2)      asm volatile("s_waitcnt vmcnt(8)" ::: "memory");
        else if (t == NT_STEPS - 2) asm volatile("s_waitcnt vmcnt(4)" ::: "memory");
        else                        asm volatile("s_waitcnt vmcnt(0)" ::: "memory");
        __builtin_amdgcn_s_barrier();
        asm volatile("" ::: "memory");       // fence: keep ds_reads below the barrier
        if (t < NT_STEPS - 3) STAGE(t + 3);
        const int bufo = (t & 3) * 16384;
        const __bf16* pA = SL + bufo + (wm * 128 + lr) * 32 + slotp * 8;
        const __bf16* pB = SL + bufo + 8192 + (wn * 64 + lr) * 32 + slotp * 8;
        bf16x8 af[8], bq_[4];
        #pragma unroll
        for (int i = 0; i < 8; ++i) af[i] = *(const bf16x8*)(pA + i * 512);
        #pragma unroll
        for (int j = 0; j < 4; ++j) bq_[j] = *(const bf16x8*)(pB + j * 512);
        __builtin_amdgcn_s_setprio(1);
        #pragma unroll
        for (int i = 0; i < 8; ++i)
            #pragma unroll
            for (int j = 0; j < 4; ++j)
                acc[i][j] = __builtin_amdgcn_mfma_f32_16x16x32_bf16(af[i], bq_[j], acc[i][j], 0, 0, 0);
        __builtin_amdgcn_s_setprio(0);
    }

    // bias (C/D: col=lane&15, row=(lane>>4)*4+reg)
    const int row0 = kslc * 4;
    #pragma unroll
    for (int i = 0; i < 8; ++i)
        #pragma unroll
        for (int r = 0; r < 4; ++r) {
            const float bb = bias[m0 + wm * 128 + i * 16 + row0 + r];
            #pragma unroll
            for (int j = 0; j < 4; ++j) acc[i][j][r] += bb;
        }

    if (MODE == 0) {
        __bf16* T = SL + wv * 2176;          // 16 x 136 per wave
        #pragma unroll
        for (int j = 0; j < 4; ++j) {
            __syncthreads();
            #pragma unroll
            for (int i = 0; i < 8; ++i)
                #pragma unroll
                for (int r = 0; r < 4; ++r)
                    T[lr * 136 + i * 16 + row0 + r] = (__bf16)acc[i][j][r];
            __syncthreads();
            const int rr = lane >> 2, seg = lane & 3;
            __bf16* dst = (__bf16*)Out + (size_t)(n0 + wn * 64 + j * 16 + rr) * KD
                          + m0 + wm * 128 + seg * 32;
            const __bf16* src = T + rr * 136 + seg * 32;
            #pragma unroll
            for (int s = 0; s < 4; ++s)
                *(bf16x8*)(dst + s * 8) = *(const bf16x8*)(src + s * 8);
        }
    } else {
        const int b_ = n0 >> 11;
        const int l0 = (n0 & 2047) + wn * 64;
        float* o = (float*)Out;
        #pragma unroll
        for (int i = 0; i < 8; ++i)
            #pragma unroll
            for (int r = 0; r < 4; ++r) {
                const int mg = m0 + wm * 128 + i * 16 + row0 + r;
                #pragma unroll
                for (int j = 0; j < 4; ++j)
                    o[((size_t)(b_ * KD + mg)) * L_SEQ + l0 + j * 16 + lr] = acc[i][j][r];
            }
    }
}

__global__ __launch_bounds__(512, 2) void gemm256_kv(
    const __bf16* __restrict__ Wk, const __bf16* __restrict__ Wv,
    const float* __restrict__ bk, const float* __restrict__ bv,
    const __bf16* __restrict__ XT, __bf16* __restrict__ Kt, __bf16* __restrict__ Vt)
{
    extern __shared__ __bf16 SL[];
    const int n0 = blockIdx.x * 256, m0 = blockIdx.y * 256;
    if (blockIdx.z == 0) gemm256_body<0>(Wk, XT, bk, Kt, m0, n0, SL);
    else                 gemm256_body<0>(Wv, XT, bv, Vt, m0, n0, SL);
}

template <int MODE>
__global__ __launch_bounds__(512, 2) void gemm256_one(
    const __bf16* __restrict__ W, const float* __restrict__ bias,
    const __bf16* __restrict__ Bt, void* __restrict__ Out)
{
    extern __shared__ __bf16 SL[];
    gemm256_body<MODE>(W, Bt, bias, Out, blockIdx.y * 256, blockIdx.x * 256, SL);
}

// ---------------- attention (all transposed, 16B loads) ----------------
__global__ __launch_bounds__(256) void attn_kernel(
    const __bf16* __restrict__ Qt, const __bf16* __restrict__ Kt,
    const __bf16* __restrict__ Vt, __bf16* __restrict__ attT)
{
    const int bid = blockIdx.x;
    const int lt = bid & 63;
    const int h = bid >> 6;
    const int tid = threadIdx.x;
    const int wave = tid >> 6, lane = tid & 63;
    const int half = lane >> 5, ln = lane & 31;
    const int n = lt * 128 + wave * 32 + ln;
    const int l = n & (L_SEQ - 1);
    const int c0 = h * 64 + half * 32;

    float q[32];
    {
        const __bf16* qp = Qt + (size_t)n * KD + c0;
        #pragma unroll
        for (int s = 0; s < 4; ++s) {
            const bf16x8 v = *(const bf16x8*)(qp + s * 8);
            #pragma unroll
            for (int j = 0; j < 8; ++j) q[s * 8 + j] = (float)v[j];
        }
    }

    float sc[10];
    #pragma unroll
    for (int w = 0; w < 5; ++w) {
        const int lw = l + w - 2;
        float acc = 0.f;
        if ((unsigned)lw < L_SEQ) {
            const __bf16* kp = Kt + (size_t)(n + w - 2) * KD + c0;
            #pragma unroll
            for (int s = 0; s < 4; ++s) {
                const bf16x8 v = *(const bf16x8*)(kp + s * 8);
                #pragma unroll
                for (int j = 0; j < 8; ++j) acc += q[s * 8 + j] * (float)v[j];
            }
        }
        sc[w] = acc;
    }
    #pragma unroll
    for (int a = 0; a < 5; ++a) {
        const __bf16* kp = Kt + ((size_t)(a + 1) * NX + n) * KD + c0;
        float acc = 0.f;
        #pragma unroll
        for (int s = 0; s < 4; ++s) {
            const bf16x8 v = *(const bf16x8*)(kp + s * 8);
            #pragma unroll
            for (int j = 0; j < 8; ++j) acc += q[s * 8 + j] * (float)v[j];
        }
        sc[5 + a] = acc;
    }

    #pragma unroll
    for (int i = 0; i < 10; ++i) {
        sc[i] += __shfl_xor(sc[i], 32);
        sc[i] *= 0.125f;
    }

    float mx = sc[0];
    #pragma unroll
    for (int i = 1; i < 10; ++i) mx = fmaxf(mx, sc[i]);
    float e[10], sum = 0.f;
    #pragma unroll
    for (int i = 0; i < 10; ++i) { e[i] = __expf(sc[i] - mx); sum += e[i]; }
    const float inv = 1.f / sum;

    float o[32];
    #pragma unroll
    for (int i = 0; i < 32; ++i) o[i] = 0.f;

    #pragma unroll
    for (int w = 0; w < 5; ++w) {
        const int lw = l + w - 2;
        if ((unsigned)lw < L_SEQ) {
            const __bf16* vp = Vt + (size_t)(n + w - 2) * KD + c0;
            #pragma unroll
            for (int s = 0; s < 4; ++s) {
                const bf16x8 v = *(const bf16x8*)(vp + s * 8);
                #pragma unroll
                for (int j = 0; j < 8; ++j) o[s * 8 + j] += e[w] * (float)v[j];
            }
        }
    }
    #pragma unroll
    for (int a = 0; a < 5; ++a) {
        const __bf16* vp = Vt + ((size_t)(a + 1) * NX + n) * KD + c0;
        #pragma unroll
        for (int s = 0; s < 4; ++s) {
            const bf16x8 v = *(const bf16x8*)(vp + s * 8);
            #pragma unroll
            for (int j = 0; j < 8; ++j) o[s * 8 + j] += e[5 + a] * (float)v[j];
        }
    }

    __bf16* dst = attT + (size_t)n * KD + c0;
    #pragma unroll
    for (int s = 0; s < 4; ++s) {
        bf16x8 t;
        #pragma unroll
        for (int j = 0; j < 8; ++j) t[j] = (__bf16)(o[s * 8 + j] * inv);
        *(bf16x8*)(dst + s * 8) = t;
    }
}

extern "C" void kernel_launch(void* const* d_in, const int* in_sizes, int n_in,
                              void* d_out, int out_size, void* d_ws, size_t ws_size,
                              hipStream_t stream)
{
    const float* x  = (const float*)d_in[0];
    const float* ax = (const float*)d_in[1];
    const float* Wq = (const float*)d_in[2];
    const float* bq = (const float*)d_in[3];
    const float* Wk = (const float*)d_in[4];
    const float* bk = (const float*)d_in[5];
    const float* Wv = (const float*)d_in[6];
    const float* bv = (const float*)d_in[7];
    const float* Wo = (const float*)d_in[8];
    const float* bo = (const float*)d_in[9];
    float* out = (float*)d_out;

    __bf16* p = (__bf16*)d_ws;
    __bf16* Wq_bf = p; p += 589824;
    __bf16* Wk_bf = p; p += 589824;
    __bf16* Wv_bf = p; p += 589824;
    __bf16* Wo_bf = p; p += 589824;
    __bf16* Qt    = p; p += (size_t)KD * NX;
    __bf16* Kt    = p; p += (size_t)KD * NALL;
    __bf16* Vt    = p; p += (size_t)KD * NALL;
    __bf16* XT    = p; p += (size_t)KD * NALL;
    __bf16* attT  = p;
    // total ws use: ~256 MB (ws is ~480 MB per harness poison fill)

    const size_t lds = 131072;

    wconv_kernel<<<dim3(576, 4), dim3(256), 0, stream>>>(Wq, Wk, Wv, Wo, Wq_bf, Wk_bf, Wv_bf, Wo_bf);
    xconv_kernel<<<dim3(768, 12), dim3(256), 0, stream>>>(x, ax, XT);

    gemm256_kv<<<dim3(192, 3, 2), dim3(512), lds, stream>>>(Wk_bf, Wv_bf, bk, bv, XT, Kt, Vt);
    gemm256_one<0><<<dim3(32, 3), dim3(512), lds, stream>>>(Wq_bf, bq, XT, Qt);

    attn_kernel<<<dim3(64 * N_HEAD), dim3(256), 0, stream>>>(Qt, Kt, Vt, attT);

    gemm256_one<1><<<dim3(32, 3), dim3(512), lds, stream>>>(Wo_bf, bo, attT, out);
}